// Round 12
// baseline (184.131 us; speedup 1.0000x reference)
//
#include <hip/hip_runtime.h>
#include <hip/hip_bf16.h>

typedef __hip_bfloat16 bf16;
typedef short bf16x8 __attribute__((ext_vector_type(8)));
typedef short bf16x4 __attribute__((ext_vector_type(4)));
typedef float floatx4 __attribute__((ext_vector_type(4)));

#define Bb 2
#define Ll 2048
#define Cc 1024
#define Hh 16
#define Dd 64
// ln(50000)/32
#define INVFREQ_LN 0.3381180763f
// (1/sqrt(D)) * log2(e) folded into Q -> attn softmax uses raw v_exp_f32 (2^x)
#define QSCALE 0.1803368801f
#define NCONV 4096

#define GLD16(gp, lp) __builtin_amdgcn_global_load_lds( \
    (const __attribute__((address_space(1))) void*)(gp), \
    (__attribute__((address_space(3))) void*)(lp), 16, 0, 0)

__device__ inline short f2bf(float f) {
    __hip_bfloat16 h = __float2bfloat16(f);
    return *reinterpret_cast<short*>(&h);
}
// fast round-to-nearest bf16; fine for finite values
__device__ inline short f2bf_rn(float f) {
    return (short)((__float_as_uint(f) + 0x8000u) >> 16);
}
// pack two f32 -> one u32 of 2 bf16 (lo = first operand), RNE
__device__ inline int cvtpk_bf16(float lo, float hi) {
    int r;
    asm("v_cvt_pk_bf16_f32 %0, %1, %2" : "=v"(r) : "v"(lo), "v"(hi));
    return r;
}
// native 2^x (gfx950 v_exp_f32 IS exp2); avoids glibc __exp2f macro collision
__device__ inline float exp2_fast(float x) {
    float r;
    asm("v_exp_f32 %0, %1" : "=v"(r) : "v"(x));
    return r;
}

// ---------------- convert fp32 -> bf16 workspace + fused per-batch mask scan ----------------
__global__ __launch_bounds__(256) void convert_scan(
    const float* __restrict__ x, const float* __restrict__ wq,
    const float* __restrict__ wk, const float* __restrict__ wv,
    const float* __restrict__ wo,
    bf16* __restrict__ xb, bf16* __restrict__ wqkv, bf16* __restrict__ wob,
    const int* __restrict__ mask, int* __restrict__ cidx, int* __restrict__ valid)
{
    if (blockIdx.x >= NCONV) {
        // ---- mask scan for batch b ----
        const int b   = blockIdx.x - NCONV;
        const int tid = threadIdx.x;
        const int base = b * Ll + tid * 8;
        int m[8]; int s = 0;
        #pragma unroll
        for (int i = 0; i < 8; i++) { m[i] = mask[base + i] ? 1 : 0; s += m[i]; }
        const int lane = tid & 63;
        int xx = s;
        #pragma unroll
        for (int off = 1; off < 64; off <<= 1) {
            int y = __shfl_up(xx, off);
            if (lane >= off) xx += y;
        }
        __shared__ int wtot[4];
        if (lane == 63) wtot[tid >> 6] = xx;
        __syncthreads();
        int wbase = 0;
        const int w = tid >> 6;
        #pragma unroll
        for (int i = 0; i < 4; i++) if (i < w) wbase += wtot[i];
        int run = wbase + (xx - s);
        #pragma unroll
        for (int i = 0; i < 8; i++) { cidx[base + i] = run; run += m[i]; }
        if (tid == 255) valid[b] = run;
        return;
    }

    const int XN = (Bb * Ll * Cc) / 8;   // 524288
    const int WN = (Cc * Cc) / 8;        // 131072
    int i = blockIdx.x * 256 + threadIdx.x;
    const float* src; bf16* dst;
    if (i < XN)               { src = x  + (size_t)i * 8;                 dst = xb   + (size_t)i * 8; }
    else if (i < XN + WN)     { int j = i - XN;        src = wq + (size_t)j * 8; dst = wqkv + (size_t)j * 8; }
    else if (i < XN + 2*WN)   { int j = i - XN - WN;   src = wk + (size_t)j * 8; dst = wqkv + (size_t)Cc*Cc     + (size_t)j * 8; }
    else if (i < XN + 3*WN)   { int j = i - XN - 2*WN; src = wv + (size_t)j * 8; dst = wqkv + (size_t)Cc*Cc*2   + (size_t)j * 8; }
    else                      { int j = i - XN - 3*WN; src = wo + (size_t)j * 8; dst = wob  + (size_t)j * 8; }
    float4 a = *reinterpret_cast<const float4*>(src);
    float4 b = *reinterpret_cast<const float4*>(src + 4);
    float vv[8] = {a.x, a.y, a.z, a.w, b.x, b.y, b.z, b.w};
    bf16x8 o;
    #pragma unroll
    for (int t = 0; t < 8; t++) o[t] = f2bf(vv[t]);
    *reinterpret_cast<bf16x8*>(dst) = o;
}

// ---------------- stage ROWSx32 bf16 tile, linear LDS dest + source-side XOR swizzle ------
// LDS granule (r, G) holds global cols ((G ^ ((r>>1)&3)) * 8 ..). Reader applies the same
// involution -> ds_read_b128 fragment reads measured at 0 bank conflicts (round 2).
template <int ROWS, int NTHREADS>
__device__ __forceinline__ void stage_swz(const bf16* __restrict__ g, int ldk,
                                          short* lds, int tid)
{
    #pragma unroll
    for (int s = 0; s < (ROWS * 4) / NTHREADS; s++) {
        const int idx = s * NTHREADS + tid;
        const int r   = idx >> 2;
        const int col = ((idx & 3) ^ ((r >> 1) & 3)) << 3;
        GLD16(g + (size_t)r * ldk + col, lds + idx * 8);
    }
}

#define VMCNT(N) asm volatile("s_waitcnt vmcnt(" #N ")" ::: "memory")

// ---------------- QKV GEMM: 64x128 (MxN) tile, ring-2, 1536 blocks = 6/CU ----------------
// 11-round finding: these GEMMs are latency-chain-bound (MfmaUtil<=22%, all pipes idle);
// the only lever that has EVER moved them is waves-resident-per-CU (out-proj 1/2/4 per CU
// = 44/41.5/35 us). QKV was stuck at 3/CU (768 blocks, 48 KiB). This shape: 24 KiB ring-2
// -> 6 blocks/CU, 24 waves/CU, double the champion's latency hiding. Counted VMCNT(3)
// per K-step (tile t+1's 3 loads in flight across the barrier; never 0 mid-loop).
// 4 waves (2M x 2N), wave tile 32x64, acc[2][4]. Scatter epilogue (verified R3-R10 form).
__global__ __launch_bounds__(256, 6) void gemm_qkv(
    const bf16* __restrict__ A, const bf16* __restrict__ W,
    bf16* __restrict__ qb, bf16* __restrict__ kb, bf16* __restrict__ vb,
    const int* __restrict__ cmask, const int* __restrict__ cidx)
{
    constexpr int K = Cc;        // 1024
    constexpr int T = K / 32;    // 32

    __shared__ __align__(16) short As[2][64 * 32];    //  8 KiB
    __shared__ __align__(16) short Bs[2][128 * 32];   // 16 KiB

    const int tid  = threadIdx.x;
    const int wave = tid >> 6;
    const int lane = tid & 63;
    const int l15  = lane & 15;
    const int quad = lane >> 4;
    const int wm   = wave >> 1;      // 2 waves in M (32 rows each)
    const int wn   = wave & 1;       // 2 waves in N (64 cols each)

    // bijective XCD-chunked swizzle: grid (24,64), nwg=1536, cpx=192
    // each XCD chunk = 8 consecutive m-rows x all 24 n-tiles -> B-panel L2 reuse x8
    const int lin = blockIdx.y * 24 + blockIdx.x;
    const int swz = (lin & 7) * 192 + (lin >> 3);
    const int m0  = (swz / 24) * 64;
    const int n0  = (swz % 24) * 128;

    const bf16* Ag = A + (size_t)m0 * K;
    const bf16* Wg = W + (size_t)n0 * K;

    const int gsw = (quad ^ ((l15 >> 1) & 3)) << 3;

    floatx4 acc[2][4];
    #pragma unroll
    for (int mt = 0; mt < 2; mt++)
        #pragma unroll
        for (int nt = 0; nt < 4; nt++)
            #pragma unroll
            for (int r = 0; r < 4; r++) acc[mt][nt][r] = 0.f;

    // prologue: tile 0 in flight (A:1 + B:2 = 3 GLD/thread)
    stage_swz<64,  256>(Ag, K, &As[0][0], tid);
    stage_swz<128, 256>(Wg, K, &Bs[0][0], tid);

    for (int t = 0; t < T; t++) {
        const int cur = t & 1;
        __builtin_amdgcn_s_barrier();   // all waves done reading buf cur^1 (iter t-1)
        if (t + 1 < T) {
            const int kk = (t + 1) << 5;
            stage_swz<64,  256>(Ag + kk, K, &As[cur ^ 1][0], tid);
            stage_swz<128, 256>(Wg + kk, K, &Bs[cur ^ 1][0], tid);
            VMCNT(3);   // tile t's 3 landed; tile t+1's 3 stay in flight
        } else {
            VMCNT(0);
        }

        const short* Ac = &As[cur][0];
        const short* Bc = &Bs[cur][0];

        bf16x8 af[2], bfr[4];
        #pragma unroll
        for (int nt = 0; nt < 4; nt++)
            bfr[nt] = *(const bf16x8*)(Bc + (wn * 64 + nt * 16 + l15) * 32 + gsw);
        #pragma unroll
        for (int mt = 0; mt < 2; mt++)
            af[mt] = *(const bf16x8*)(Ac + (wm * 32 + mt * 16 + l15) * 32 + gsw);

        #pragma unroll
        for (int mt = 0; mt < 2; mt++)
            #pragma unroll
            for (int nt = 0; nt < 4; nt++)
                acc[mt][nt] = __builtin_amdgcn_mfma_f32_16x16x32_bf16(
                    af[mt], bfr[nt], acc[mt][nt], 0, 0, 0);
    }

    // epilogue: row = m0 + wm*32 + mt*16 + quad*4 + r, col = n0 + wn*64 + nt*16 + l15
    const int colbase = n0 + wn * 64;          // 64-aligned -> one (which,h)
    const int which   = colbase >> 10;         // 0=q, 1=k, 2=v
    const int hh      = (colbase & (Cc - 1)) >> 6;
    if (which == 2) {
        // V compacted+transposed+swizzled: element (d, c) at
        // head + d*L + (c&~63) + ((((c>>3)&7) ^ (d&7))<<3) + (c&7)
        #pragma unroll
        for (int mt = 0; mt < 2; mt++)
            #pragma unroll
            for (int r = 0; r < 4; r++) {
                int row = m0 + wm * 32 + mt * 16 + quad * 4 + r;
                int b = row >> 11, l = row & (Ll - 1);
                if (cmask[b * Ll + l]) {
                    int c = cidx[b * Ll + l];
                    size_t head = (size_t)(b * Hh + hh) * Dd * Ll;
                    int lbase = (c & ~63) | (c & 7);
                    int lg    = (c >> 3) & 7;
                    #pragma unroll
                    for (int nt = 0; nt < 4; nt++) {
                        int d = nt * 16 + l15;
                        int pos = lbase | ((lg ^ (d & 7)) << 3);
                        vb[head + (size_t)d * Ll + pos] = __float2bfloat16(acc[mt][nt][r]);
                    }
                }
            }
    } else {
        bf16* dst = which ? kb : qb;
        const float qs = which ? 1.0f : QSCALE;
        const float base0 = __expf(-(float)l15 * INVFREQ_LN);
        const float base1 = __expf(-(float)(l15 + 16) * INVFREQ_LN);
        #pragma unroll
        for (int mt = 0; mt < 2; mt++)
            #pragma unroll
            for (int r = 0; r < 4; r++) {
                int row = m0 + wm * 32 + mt * 16 + quad * 4 + r;
                int b = row >> 11, l = row & (Ll - 1);
                int cm = 1, c = l;
                if (which == 1) {
                    cm = cmask[b * Ll + l];
                    c  = cidx[b * Ll + l];
                }
                if (cm) {
                    size_t rb = ((size_t)(b * Hh + hh) * Ll + c) * Dd;
                    #pragma unroll
                    for (int nt2 = 0; nt2 < 2; nt2++) {
                        float fr = (float)l * (nt2 ? base1 : base0);
                        float sn, cs;
                        __sincosf(fr, &sn, &cs);
                        float x1 = acc[mt][nt2][r];
                        float x2 = acc[mt][nt2 + 2][r];
                        float o1 = (x1 * cs - x2 * sn) * qs;
                        float o2 = (x2 * cs + x1 * sn) * qs;
                        int d1 = nt2 * 16 + l15;
                        int d2 = d1 + 32;
                        if (which == 1) {
                            int sw = c & 7;
                            int a1 = ((((d1 >> 3) ^ sw)) << 3) | (d1 & 7);
                            int a2 = ((((d2 >> 3) ^ sw)) << 3) | (d2 & 7);
                            dst[rb + a1] = __float2bfloat16(o1);
                            dst[rb + a2] = __float2bfloat16(o2);
                        } else {
                            dst[rb + d1] = __float2bfloat16(o1);
                            dst[rb + d2] = __float2bfloat16(o2);
                        }
                    }
                }
            }
    }
}

// ---------------- out-proj GEMM: 64x64 tile, ring-3 counted, 1024 blocks ~4/CU ----------
__global__ __launch_bounds__(256, 4) void gemm_out(
    const bf16* __restrict__ A, const bf16* __restrict__ W,
    float* __restrict__ outf, const float* __restrict__ bias)
{
    constexpr int K = Cc, N = Cc;
    constexpr int T = K / 32;    // 32

    __shared__ __align__(16) short As[3][64 * 32];    // 12 KiB
    __shared__ __align__(16) short Bs[3][64 * 32];    // 12 KiB

    const int tid  = threadIdx.x;
    const int wave = tid >> 6;
    const int lane = tid & 63;
    const int l15  = lane & 15;
    const int quad = lane >> 4;
    const int wm   = wave >> 1;      // 2 waves in M (32 rows each)
    const int wn   = wave & 1;       // 2 waves in N (32 cols each)

    // bijective XCD-chunked swizzle: grid (16,64), nwg=1024, cpx=128
    const int lin = blockIdx.y * 16 + blockIdx.x;
    const int swz = (lin & 7) * 128 + (lin >> 3);
    const int m0  = (swz >> 4) * 64;
    const int n0  = (swz & 15) * 64;

    const bf16* Ag = A + (size_t)m0 * K;
    const bf16* Wg = W + (size_t)n0 * K;

    const int gsw = (quad ^ ((l15 >> 1) & 3)) << 3;

    floatx4 acc[2][2];
    #pragma unroll
    for (int mt = 0; mt < 2; mt++)
        #pragma unroll
        for (int nt = 0; nt < 2; nt++)
            #pragma unroll
            for (int r = 0; r < 4; r++) acc[mt][nt][r] = 0.f;

    // prologue: tiles 0 and 1 in flight (2 GLD/thread each); wait tile 0
    stage_swz<64, 256>(Ag,      K, &As[0][0], tid);
    stage_swz<64, 256>(Wg,      K, &Bs[0][0], tid);
    stage_swz<64, 256>(Ag + 32, K, &As[1][0], tid);
    stage_swz<64, 256>(Wg + 32, K, &Bs[1][0], tid);
    VMCNT(2);
    __builtin_amdgcn_s_barrier();

    int cur = 0;
    for (int t = 0; t < T; t++) {
        const short* Ac = &As[0][0] + cur * (64 * 32);
        const short* Bc = &Bs[0][0] + cur * (64 * 32);

        if (t + 2 < T) {
            int nb = cur + 2; if (nb >= 3) nb -= 3;
            const int kk = (t + 2) << 5;
            stage_swz<64, 256>(Ag + kk, K, &As[nb][0], tid);
            stage_swz<64, 256>(Wg + kk, K, &Bs[nb][0], tid);
        }

        bf16x8 af[2], bfr[2];
        #pragma unroll
        for (int mt = 0; mt < 2; mt++)
            af[mt] = *(const bf16x8*)(Ac + (wm * 32 + mt * 16 + l15) * 32 + gsw);
        #pragma unroll
        for (int nt = 0; nt < 2; nt++)
            bfr[nt] = *(const bf16x8*)(Bc + (wn * 32 + nt * 16 + l15) * 32 + gsw);

        #pragma unroll
        for (int mt = 0; mt < 2; mt++)
            #pragma unroll
            for (int nt = 0; nt < 2; nt++)
                acc[mt][nt] = __builtin_amdgcn_mfma_f32_16x16x32_bf16(
                    af[mt], bfr[nt], acc[mt][nt], 0, 0, 0);

        if (t + 2 < T) { VMCNT(2); }
        else           { VMCNT(0); }
        __builtin_amdgcn_s_barrier();

        cur++; if (cur == 3) cur = 0;
    }

    // epilogue: row = m0 + wm*32 + mt*16 + quad*4 + r, col = n0 + wn*32 + nt*16 + l15
    #pragma unroll
    for (int mt = 0; mt < 2; mt++)
        #pragma unroll
        for (int r = 0; r < 4; r++) {
            int row = m0 + wm * 32 + mt * 16 + quad * 4 + r;
            #pragma unroll
            for (int nt = 0; nt < 2; nt++) {
                int col = n0 + wn * 32 + nt * 16 + l15;
                outf[(size_t)row * N + col] = acc[mt][nt][r] + bias[col];
            }
        }
}

// ---------------- Flash attention v3: KVBLK=128, counted vmcnt, exp2 + cvt_pk softmax ----
#define KVB 128

__global__ __launch_bounds__(512) void attn_mfma(
    const bf16* __restrict__ q, const bf16* __restrict__ k, const bf16* __restrict__ vt,
    const int* __restrict__ valid, bf16* __restrict__ ctx)
{
    __shared__ __align__(16) short Ks[2][KVB * 64];   // 32 KiB
    __shared__ __align__(16) short Vs[2][KVB * 64];   // 32 KiB (two 64-key chunks stacked)
    __shared__ __align__(16) short Ps[8][16 * 64];    // 16 KiB, XOR-swizzled

    const int tid  = threadIdx.x;
    const int wave = tid >> 6;
    const int lane = tid & 63;
    const int l15  = lane & 15;
    const int quad = lane >> 4;

    const int bh = blockIdx.x & 31;           // (b*H + h) -> fixed XCD per head
    const int q0 = (blockIdx.x >> 5) << 7;    // 128-query tile start
    const int b  = bh >> 4;
    const int h  = bh & (Hh - 1);

    const int nvalid = valid[b];
    const int ntiles = (nvalid + KVB - 1) >> 7;

    const short* qb  = (const short*)(q  + (size_t)bh * Ll * Dd);
    const short* kb  = (const short*)(k  + (size_t)bh * Ll * Dd);
    const short* vtb = (const short*)(vt + (size_t)bh * Dd * Ll);

    // Q fragment: wave's 16 rows (linear layout)
    const int qrow = q0 + wave * 16 + l15;
    bf16x8 qa0 = *(const bf16x8*)(qb + (size_t)qrow * Dd + quad * 8);
    bf16x8 qa1 = *(const bf16x8*)(qb + (size_t)qrow * Dd + 32 + quad * 8);

    // swizzled group offsets (shorts) within a 64-short row, row&7 == l15&7
    const int g0 = ((quad ^ (l15 & 7)) << 3);
    const int g1 = (((quad + 4) ^ (l15 & 7)) << 3);

    // staging: K rows are keys (64 shorts each); thread covers 16B at tid*8 and +4096.
    // V transposed [d][key]: thread (d=tid>>3, grp=tid&7); chunk c at LDS offset c*4096.
    const short* vgp = vtb + (size_t)(tid >> 3) * Ll + ((tid & 7) << 3);
    short* ksl = &Ks[0][0] + tid * 8;
    short* vsl = &Vs[0][0] + tid * 8;
    const int lbuf = KVB * 64;          // 8192 shorts per buffer

    floatx4 O[4];
    float l_r = 0.f;
    #pragma unroll
    for (int nt = 0; nt < 4; nt++)
        #pragma unroll
        for (int r = 0; r < 4; r++) O[nt][r] = 0.f;

    // prologue: stage tile 0 (4 GLDs)
    GLD16(kb + tid * 8,        ksl);
    GLD16(kb + 4096 + tid * 8, ksl + 4096);
    GLD16(vgp,                 vsl);
    GLD16(vgp + 64,            vsl + 4096);

    short* Pw = &Ps[wave][0];

    for (int t = 0; t < ntiles; t++) {
        const int cur = t & 1;
        __builtin_amdgcn_s_barrier();   // all waves done reading buf cur^1
        if (t + 1 < ntiles) {
            const size_t s1 = (size_t)(t + 1) * KVB;
            GLD16(kb + s1 * 64 + tid * 8,        ksl + (cur ^ 1) * lbuf);
            GLD16(kb + s1 * 64 + 4096 + tid * 8, ksl + (cur ^ 1) * lbuf + 4096);
            GLD16(vgp + s1,                      vsl + (cur ^ 1) * lbuf);
            GLD16(vgp + s1 + 64,                 vsl + (cur ^ 1) * lbuf + 4096);
            VMCNT(4);   // tile t's 4 landed; tile t+1's 4 stay in flight
        } else {
            VMCNT(0);
        }

        const short* Kc = &Ks[cur][0];
        const short* Vc = &Vs[cur][0];

        #pragma unroll
        for (int c = 0; c < 2; c++) {
            // ---- S^T = K Q^T for 64-key chunk c: lane holds S[q=l15][key c*64+nt*16+quad*4+r]
            floatx4 S[4];
            #pragma unroll
            for (int nt = 0; nt < 4; nt++) {
                const short* krow = Kc + (c * 64 + nt * 16 + l15) * 64;
                bf16x8 ka0 = *(const bf16x8*)(krow + g0);
                bf16x8 ka1 = *(const bf16x8*)(krow + g1);
                floatx4 acc; acc[0] = acc[1] = acc[2] = acc[3] = 0.f;
                acc = __builtin_amdgcn_mfma_f32_16x16x32_bf16(ka0, qa0, acc, 0, 0, 0);
                acc = __builtin_amdgcn_mfma_f32_16x16x32_bf16(ka1, qa1, acc, 0, 0, 0);
                S[nt] = acc;
            }

            // ---- softmax: p = 2^S (log2e pre-folded into Q); mask keys >= nvalid ----
            const int kglob0 = t * KVB + c * 64;
            if (kglob0 + 64 <= nvalid) {
                #pragma unroll
                for (int nt = 0; nt < 4; nt++) {
                    float p0 = exp2_fast(S[nt][0]);
                    float p1 = exp2_fast(S[nt][1]);
                    float p2 = exp2_fast(S[nt][2]);
                    float p3 = exp2_fast(S[nt][3]);
                    l_r += (p0 + p1) + (p2 + p3);
                    int2 pw;
                    pw.x = cvtpk_bf16(p0, p1);
                    pw.y = cvtpk_bf16(p2, p3);
                    int grp = (2 * nt + (quad >> 1)) ^ (l15 & 7);
                    *(int2*)&Pw[l15 * 64 + (grp << 3) + ((quad & 1) << 2)] = pw;
                }
            } else {
                const int kb0 = kglob0 + quad * 4;
                #pragma unroll
                for (int nt = 0; nt < 4; nt++) {
                    float p[4];
                    #pragma unroll
                    for (int r = 0; r < 4; r++) {
                        p[r] = (kb0 + nt * 16 + r < nvalid) ? exp2_fast(S[nt][r]) : 0.f;
                        l_r += p[r];
                    }
                    int2 pw;
                    pw.x = cvtpk_bf16(p[0], p[1]);
                    pw.y = cvtpk_bf16(p[2], p[3]);
                    int grp = (2 * nt + (quad >> 1)) ^ (l15 & 7);
                    *(int2*)&Pw[l15 * 64 + (grp << 3) + ((quad & 1) << 2)] = pw;
                }
            }

            // ---- O^T += V^T P^T for chunk c ----
            bf16x8 pb0 = *(const bf16x8*)&Pw[l15 * 64 + ((quad ^ (l15 & 7)) << 3)];
            bf16x8 pb1 = *(const bf16x8*)&Pw[l15 * 64 + (((4 + quad) ^ (l15 & 7)) << 3)];
            #pragma unroll
            for (int nt = 0; nt < 4; nt++) {
                const short* vrow = Vc + c * 4096 + (nt * 16 + l15) * 64;
                bf16x8 va0 = *(const bf16x8*)(vrow + g0);
                bf16x8 va1 = *(const bf16x8*)(vrow + g1);
                O[nt] = __builtin_amdgcn_mfma_f32_16x16x32_bf16(va0, pb0, O[nt], 0, 0, 0);
                O[nt] = __builtin_amdgcn_mfma_f32_16x16x32_bf16(va1, pb1, O[nt], 0, 0, 0);
            }
        }
    }

    // ---- row-sum (quads hold same q) ----
    float l = l_r;
    l += __shfl_xor(l, 16);
    l += __shfl_xor(l, 32);
    const float inv = 1.0f / l;

    // ---- write ctx: lane holds O[q=l15][d=nt*16+quad*4+r] -> b64 stores ----
    {
        int row = q0 + wave * 16 + l15;
        short* cp = (short*)ctx + ((size_t)(b * Ll + row)) * Cc + h * Dd;
        #pragma unroll
        for (int nt = 0; nt < 4; nt++) {
            int2 ov;
            ov.x = cvtpk_bf16(O[nt][0] * inv, O[nt][1] * inv);
            ov.y = cvtpk_bf16(O[nt][2] * inv, O[nt][3] * inv);
            *(int2*)&cp[nt * 16 + quad * 4] = ov;
        }
    }
}

extern "C" void kernel_launch(void* const* d_in, const int* in_sizes, int n_in,
                              void* d_out, int out_size, void* d_ws, size_t ws_size,
                              hipStream_t stream) {
    const float* x    = (const float*)d_in[0];
    const int*   mask = (const int*)d_in[1];
    const float* Wq   = (const float*)d_in[2];
    const float* Wk   = (const float*)d_in[3];
    const float* Wv   = (const float*)d_in[4];
    const float* Wo   = (const float*)d_in[5];
    const float* bo   = (const float*)d_in[6];
    float* out = (float*)d_out;

    const size_t per = (size_t)Bb * Hh * Ll * Dd;   // 4 Mi elements
    bf16* qbuf = (bf16*)d_ws;
    bf16* kbuf = qbuf + per;            // compacted + swizzled
    bf16* vbuf = kbuf + per;            // compacted + transposed [B,H,D,L'] + swizzled
    bf16* xb   = vbuf + per;            // also used as ctx after x is dead
    bf16* wqkv = xb + per;              // [3072, 1024]
    bf16* wob  = wqkv + (size_t)3 * Cc * Cc;
    int*  cidx   = (int*)(wob + (size_t)Cc * Cc);
    int*  cvalid = cidx + Bb * Ll;
    bf16* ctx  = xb;

    const int M = Bb * Ll;   // 4096

    convert_scan<<<NCONV + Bb, 256, 0, stream>>>(
        x, Wq, Wk, Wv, Wo, xb, wqkv, wob, mask, cidx, cvalid);

    // fused QKV projection + RoPE + Q-scale(+log2e) + K/V compaction/swizzle + V-transpose
    // 64x128 tile, ring-2 counted-vmcnt, 256 threads, 1536 blocks = 6 blocks/CU
    dim3 gQKV(3 * Cc / 128, M / 64);    // (24, 64) = 1536 blocks
    gemm_qkv<<<gQKV, 256, 0, stream>>>(xb, wqkv, qbuf, kbuf, vbuf, mask, cidx);

    attn_mfma<<<Bb * Hh * (Ll / 128), 512, 0, stream>>>(qbuf, kbuf, vbuf, cvalid, ctx);

    // output projection: 64x64 tile, 1024 blocks ~4/CU
    dim3 gOut(Cc / 64, M / 64);         // (16, 64) = 1024 blocks
    gemm_out<<<gOut, 256, 0, stream>>>(ctx, wob, out, bo);
}

// Round 13
// 170.720 us; speedup vs baseline: 1.0786x; 1.0786x over previous
//
#include <hip/hip_runtime.h>
#include <hip/hip_bf16.h>

typedef __hip_bfloat16 bf16;
typedef short bf16x8 __attribute__((ext_vector_type(8)));
typedef short bf16x4 __attribute__((ext_vector_type(4)));
typedef float floatx4 __attribute__((ext_vector_type(4)));

#define Bb 2
#define Ll 2048
#define Cc 1024
#define Hh 16
#define Dd 64
// ln(50000)/32
#define INVFREQ_LN 0.3381180763f
// (1/sqrt(D)) * log2(e) folded into Q -> attn softmax uses raw v_exp_f32 (2^x)
#define QSCALE 0.1803368801f
#define NCONV 4096

#define GLD16(gp, lp) __builtin_amdgcn_global_load_lds( \
    (const __attribute__((address_space(1))) void*)(gp), \
    (__attribute__((address_space(3))) void*)(lp), 16, 0, 0)

__device__ inline short f2bf(float f) {
    __hip_bfloat16 h = __float2bfloat16(f);
    return *reinterpret_cast<short*>(&h);
}
// fast round-to-nearest bf16; fine for finite values
__device__ inline short f2bf_rn(float f) {
    return (short)((__float_as_uint(f) + 0x8000u) >> 16);
}
// pack two f32 -> one u32 of 2 bf16 (lo = first operand), RNE
__device__ inline int cvtpk_bf16(float lo, float hi) {
    int r;
    asm("v_cvt_pk_bf16_f32 %0, %1, %2" : "=v"(r) : "v"(lo), "v"(hi));
    return r;
}
// native 2^x (gfx950 v_exp_f32 IS exp2); avoids glibc __exp2f macro collision
__device__ inline float exp2_fast(float x) {
    float r;
    asm("v_exp_f32 %0, %1" : "=v"(r) : "v"(x));
    return r;
}

// ---------------- convert fp32 -> bf16 workspace + fused per-batch mask scan ----------------
__global__ __launch_bounds__(256) void convert_scan(
    const float* __restrict__ x, const float* __restrict__ wq,
    const float* __restrict__ wk, const float* __restrict__ wv,
    const float* __restrict__ wo,
    bf16* __restrict__ xb, bf16* __restrict__ wqkv, bf16* __restrict__ wob,
    const int* __restrict__ mask, int* __restrict__ cidx, int* __restrict__ valid)
{
    if (blockIdx.x >= NCONV) {
        // ---- mask scan for batch b ----
        const int b   = blockIdx.x - NCONV;
        const int tid = threadIdx.x;
        const int base = b * Ll + tid * 8;
        int m[8]; int s = 0;
        #pragma unroll
        for (int i = 0; i < 8; i++) { m[i] = mask[base + i] ? 1 : 0; s += m[i]; }
        const int lane = tid & 63;
        int xx = s;
        #pragma unroll
        for (int off = 1; off < 64; off <<= 1) {
            int y = __shfl_up(xx, off);
            if (lane >= off) xx += y;
        }
        __shared__ int wtot[4];
        if (lane == 63) wtot[tid >> 6] = xx;
        __syncthreads();
        int wbase = 0;
        const int w = tid >> 6;
        #pragma unroll
        for (int i = 0; i < 4; i++) if (i < w) wbase += wtot[i];
        int run = wbase + (xx - s);
        #pragma unroll
        for (int i = 0; i < 8; i++) { cidx[base + i] = run; run += m[i]; }
        if (tid == 255) valid[b] = run;
        return;
    }

    const int XN = (Bb * Ll * Cc) / 8;   // 524288
    const int WN = (Cc * Cc) / 8;        // 131072
    int i = blockIdx.x * 256 + threadIdx.x;
    const float* src; bf16* dst;
    if (i < XN)               { src = x  + (size_t)i * 8;                 dst = xb   + (size_t)i * 8; }
    else if (i < XN + WN)     { int j = i - XN;        src = wq + (size_t)j * 8; dst = wqkv + (size_t)j * 8; }
    else if (i < XN + 2*WN)   { int j = i - XN - WN;   src = wk + (size_t)j * 8; dst = wqkv + (size_t)Cc*Cc     + (size_t)j * 8; }
    else if (i < XN + 3*WN)   { int j = i - XN - 2*WN; src = wv + (size_t)j * 8; dst = wqkv + (size_t)Cc*Cc*2   + (size_t)j * 8; }
    else                      { int j = i - XN - 3*WN; src = wo + (size_t)j * 8; dst = wob  + (size_t)j * 8; }
    float4 a = *reinterpret_cast<const float4*>(src);
    float4 b = *reinterpret_cast<const float4*>(src + 4);
    float vv[8] = {a.x, a.y, a.z, a.w, b.x, b.y, b.z, b.w};
    bf16x8 o;
    #pragma unroll
    for (int t = 0; t < 8; t++) o[t] = f2bf(vv[t]);
    *reinterpret_cast<bf16x8*>(dst) = o;
}

// ---------------- stage ROWSx32 bf16 tile, linear LDS dest + source-side XOR swizzle ------
// LDS granule (r, G) holds global cols ((G ^ ((r>>1)&3)) * 8 ..). Reader applies the same
// involution -> ds_read_b128 fragment reads measured at 0 bank conflicts (round 2).
template <int ROWS, int NTHREADS>
__device__ __forceinline__ void stage_swz(const bf16* __restrict__ g, int ldk,
                                          short* lds, int tid)
{
    #pragma unroll
    for (int s = 0; s < (ROWS * 4) / NTHREADS; s++) {
        const int idx = s * NTHREADS + tid;
        const int r   = idx >> 2;
        const int col = ((idx & 3) ^ ((r >> 1) & 3)) << 3;
        GLD16(g + (size_t)r * ldk + col, lds + idx * 8);
    }
}

#define VMCNT(N) asm volatile("s_waitcnt vmcnt(" #N ")" ::: "memory")

// ---------------- QKV GEMM: 128x128 tile, ring-3, 512 threads (8 waves), 3 blocks/CU ----
// R12 lesson: occupancy gained by SHRINKING tiles doubles FETCH and loses. This keeps the
// champion's tile geometry (128^2, 48 KiB ring-3, 768 blocks, FETCH ~28.8 MB) and raises
// wave-residency instead: 512 threads -> 24 waves/CU (vs champion's 12). Per-wave chain
// halves (32x64 wave tile: 6 ds_read_b128 + 8 MFMA per K-step). Counted VMCNT(2) per
// K-step (tile t+2's 2 loads in flight; never 0 mid-loop). Wave-N stays 64-wide so the
// verified RoPE/compact/V-transpose epilogue carries over (wm=wave>>1, mt<2).
__global__ __launch_bounds__(512, 3) void gemm_qkv(
    const bf16* __restrict__ A, const bf16* __restrict__ W,
    bf16* __restrict__ qb, bf16* __restrict__ kb, bf16* __restrict__ vb,
    const int* __restrict__ cmask, const int* __restrict__ cidx)
{
    constexpr int K = Cc;        // 1024
    constexpr int T = K / 32;    // 32

    __shared__ __align__(16) short As[3][128 * 32];
    __shared__ __align__(16) short Bs[3][128 * 32];

    const int tid  = threadIdx.x;
    const int wave = tid >> 6;
    const int lane = tid & 63;
    const int l15  = lane & 15;
    const int quad = lane >> 4;
    const int wm   = wave >> 1;        // 4 waves in M (32 rows each)
    const int wn   = wave & 1;         // 2 waves in N (64 cols each)

    // bijective XCD-chunked swizzle: grid (24,32), nwg=768, cpx=96
    const int lin = blockIdx.y * 24 + blockIdx.x;
    const int swz = (lin & 7) * 96 + (lin >> 3);
    const int m0  = (swz / 24) * 128;
    const int n0  = (swz % 24) * 128;

    const bf16* Ag = A + (size_t)m0 * K;
    const bf16* Wg = W + (size_t)n0 * K;

    const int gsw = (quad ^ ((l15 >> 1) & 3)) << 3;

    floatx4 acc[2][4];
    #pragma unroll
    for (int mt = 0; mt < 2; mt++)
        #pragma unroll
        for (int nt = 0; nt < 4; nt++)
            #pragma unroll
            for (int r = 0; r < 4; r++) acc[mt][nt][r] = 0.f;

    // prologue: tiles 0 and 1 in flight (2 GLD/thread each); wait tile 0 only
    stage_swz<128, 512>(Ag,      K, &As[0][0], tid);
    stage_swz<128, 512>(Wg,      K, &Bs[0][0], tid);
    stage_swz<128, 512>(Ag + 32, K, &As[1][0], tid);
    stage_swz<128, 512>(Wg + 32, K, &Bs[1][0], tid);
    VMCNT(2);
    __builtin_amdgcn_s_barrier();

    int cur = 0;
    for (int t = 0; t < T; t++) {
        const short* Ac = &As[0][0] + cur * (128 * 32);
        const short* Bc = &Bs[0][0] + cur * (128 * 32);

        if (t + 2 < T) {
            int nb = cur + 2; if (nb >= 3) nb -= 3;
            const int kk = (t + 2) << 5;
            stage_swz<128, 512>(Ag + kk, K, &As[nb][0], tid);
            stage_swz<128, 512>(Wg + kk, K, &Bs[nb][0], tid);
        }

        bf16x8 af[2], bfr[4];
        #pragma unroll
        for (int nt = 0; nt < 4; nt++)
            bfr[nt] = *(const bf16x8*)(Bc + (wn * 64 + nt * 16 + l15) * 32 + gsw);
        #pragma unroll
        for (int mt = 0; mt < 2; mt++)
            af[mt] = *(const bf16x8*)(Ac + (wm * 32 + mt * 16 + l15) * 32 + gsw);

        #pragma unroll
        for (int mt = 0; mt < 2; mt++)
            #pragma unroll
            for (int nt = 0; nt < 4; nt++)
                acc[mt][nt] = __builtin_amdgcn_mfma_f32_16x16x32_bf16(
                    af[mt], bfr[nt], acc[mt][nt], 0, 0, 0);

        if (t + 2 < T) { VMCNT(2); }   // tile t+1 landed; t+2's 2 loads stay in flight
        else           { VMCNT(0); }
        __builtin_amdgcn_s_barrier();

        cur++; if (cur == 3) cur = 0;
    }

    // epilogue: row = m0 + wm*32 + mt*16 + quad*4 + r, col = n0 + wn*64 + nt*16 + l15
    const int colbase = n0 + wn * 64;          // 64-aligned -> one (which,h)
    const int which   = colbase >> 10;         // 0=q, 1=k, 2=v
    const int hh      = (colbase & (Cc - 1)) >> 6;
    if (which == 2) {
        // V compacted+transposed+swizzled: element (d, c) at
        // head + d*L + (c&~63) + ((((c>>3)&7) ^ (d&7))<<3) + (c&7)
        #pragma unroll
        for (int mt = 0; mt < 2; mt++)
            #pragma unroll
            for (int r = 0; r < 4; r++) {
                int row = m0 + wm * 32 + mt * 16 + quad * 4 + r;
                int b = row >> 11, l = row & (Ll - 1);
                if (cmask[b * Ll + l]) {
                    int c = cidx[b * Ll + l];
                    size_t head = (size_t)(b * Hh + hh) * Dd * Ll;
                    int lbase = (c & ~63) | (c & 7);
                    int lg    = (c >> 3) & 7;
                    #pragma unroll
                    for (int nt = 0; nt < 4; nt++) {
                        int d = nt * 16 + l15;
                        int pos = lbase | ((lg ^ (d & 7)) << 3);
                        vb[head + (size_t)d * Ll + pos] = __float2bfloat16(acc[mt][nt][r]);
                    }
                }
            }
    } else {
        bf16* dst = which ? kb : qb;
        const float qs = which ? 1.0f : QSCALE;
        const float base0 = __expf(-(float)l15 * INVFREQ_LN);
        const float base1 = __expf(-(float)(l15 + 16) * INVFREQ_LN);
        #pragma unroll
        for (int mt = 0; mt < 2; mt++)
            #pragma unroll
            for (int r = 0; r < 4; r++) {
                int row = m0 + wm * 32 + mt * 16 + quad * 4 + r;
                int b = row >> 11, l = row & (Ll - 1);
                int cm = 1, c = l;
                if (which == 1) {
                    cm = cmask[b * Ll + l];
                    c  = cidx[b * Ll + l];
                }
                if (cm) {
                    size_t rb = ((size_t)(b * Hh + hh) * Ll + c) * Dd;
                    #pragma unroll
                    for (int nt2 = 0; nt2 < 2; nt2++) {
                        float fr = (float)l * (nt2 ? base1 : base0);
                        float sn, cs;
                        __sincosf(fr, &sn, &cs);
                        float x1 = acc[mt][nt2][r];
                        float x2 = acc[mt][nt2 + 2][r];
                        float o1 = (x1 * cs - x2 * sn) * qs;
                        float o2 = (x2 * cs + x1 * sn) * qs;
                        int d1 = nt2 * 16 + l15;
                        int d2 = d1 + 32;
                        if (which == 1) {
                            int sw = c & 7;
                            int a1 = ((((d1 >> 3) ^ sw)) << 3) | (d1 & 7);
                            int a2 = ((((d2 >> 3) ^ sw)) << 3) | (d2 & 7);
                            dst[rb + a1] = __float2bfloat16(o1);
                            dst[rb + a2] = __float2bfloat16(o2);
                        } else {
                            dst[rb + d1] = __float2bfloat16(o1);
                            dst[rb + d2] = __float2bfloat16(o2);
                        }
                    }
                }
            }
    }
}

// ---------------- out-proj GEMM: 64x64 tile, ring-3 counted, 1024 blocks ~4/CU ----------
__global__ __launch_bounds__(256, 4) void gemm_out(
    const bf16* __restrict__ A, const bf16* __restrict__ W,
    float* __restrict__ outf, const float* __restrict__ bias)
{
    constexpr int K = Cc, N = Cc;
    constexpr int T = K / 32;    // 32

    __shared__ __align__(16) short As[3][64 * 32];    // 12 KiB
    __shared__ __align__(16) short Bs[3][64 * 32];    // 12 KiB

    const int tid  = threadIdx.x;
    const int wave = tid >> 6;
    const int lane = tid & 63;
    const int l15  = lane & 15;
    const int quad = lane >> 4;
    const int wm   = wave >> 1;      // 2 waves in M (32 rows each)
    const int wn   = wave & 1;       // 2 waves in N (32 cols each)

    // bijective XCD-chunked swizzle: grid (16,64), nwg=1024, cpx=128
    const int lin = blockIdx.y * 16 + blockIdx.x;
    const int swz = (lin & 7) * 128 + (lin >> 3);
    const int m0  = (swz >> 4) * 64;
    const int n0  = (swz & 15) * 64;

    const bf16* Ag = A + (size_t)m0 * K;
    const bf16* Wg = W + (size_t)n0 * K;

    const int gsw = (quad ^ ((l15 >> 1) & 3)) << 3;

    floatx4 acc[2][2];
    #pragma unroll
    for (int mt = 0; mt < 2; mt++)
        #pragma unroll
        for (int nt = 0; nt < 2; nt++)
            #pragma unroll
            for (int r = 0; r < 4; r++) acc[mt][nt][r] = 0.f;

    // prologue: tiles 0 and 1 in flight (2 GLD/thread each); wait tile 0
    stage_swz<64, 256>(Ag,      K, &As[0][0], tid);
    stage_swz<64, 256>(Wg,      K, &Bs[0][0], tid);
    stage_swz<64, 256>(Ag + 32, K, &As[1][0], tid);
    stage_swz<64, 256>(Wg + 32, K, &Bs[1][0], tid);
    VMCNT(2);
    __builtin_amdgcn_s_barrier();

    int cur = 0;
    for (int t = 0; t < T; t++) {
        const short* Ac = &As[0][0] + cur * (64 * 32);
        const short* Bc = &Bs[0][0] + cur * (64 * 32);

        if (t + 2 < T) {
            int nb = cur + 2; if (nb >= 3) nb -= 3;
            const int kk = (t + 2) << 5;
            stage_swz<64, 256>(Ag + kk, K, &As[nb][0], tid);
            stage_swz<64, 256>(Wg + kk, K, &Bs[nb][0], tid);
        }

        bf16x8 af[2], bfr[2];
        #pragma unroll
        for (int mt = 0; mt < 2; mt++)
            af[mt] = *(const bf16x8*)(Ac + (wm * 32 + mt * 16 + l15) * 32 + gsw);
        #pragma unroll
        for (int nt = 0; nt < 2; nt++)
            bfr[nt] = *(const bf16x8*)(Bc + (wn * 32 + nt * 16 + l15) * 32 + gsw);

        #pragma unroll
        for (int mt = 0; mt < 2; mt++)
            #pragma unroll
            for (int nt = 0; nt < 2; nt++)
                acc[mt][nt] = __builtin_amdgcn_mfma_f32_16x16x32_bf16(
                    af[mt], bfr[nt], acc[mt][nt], 0, 0, 0);

        if (t + 2 < T) { VMCNT(2); }
        else           { VMCNT(0); }
        __builtin_amdgcn_s_barrier();

        cur++; if (cur == 3) cur = 0;
    }

    // epilogue: row = m0 + wm*32 + mt*16 + quad*4 + r, col = n0 + wn*32 + nt*16 + l15
    #pragma unroll
    for (int mt = 0; mt < 2; mt++)
        #pragma unroll
        for (int r = 0; r < 4; r++) {
            int row = m0 + wm * 32 + mt * 16 + quad * 4 + r;
            #pragma unroll
            for (int nt = 0; nt < 2; nt++) {
                int col = n0 + wn * 32 + nt * 16 + l15;
                outf[(size_t)row * N + col] = acc[mt][nt][r] + bias[col];
            }
        }
}

// ---------------- Flash attention v3: KVBLK=128, counted vmcnt, exp2 + cvt_pk softmax ----
#define KVB 128

__global__ __launch_bounds__(512) void attn_mfma(
    const bf16* __restrict__ q, const bf16* __restrict__ k, const bf16* __restrict__ vt,
    const int* __restrict__ valid, bf16* __restrict__ ctx)
{
    __shared__ __align__(16) short Ks[2][KVB * 64];   // 32 KiB
    __shared__ __align__(16) short Vs[2][KVB * 64];   // 32 KiB (two 64-key chunks stacked)
    __shared__ __align__(16) short Ps[8][16 * 64];    // 16 KiB, XOR-swizzled

    const int tid  = threadIdx.x;
    const int wave = tid >> 6;
    const int lane = tid & 63;
    const int l15  = lane & 15;
    const int quad = lane >> 4;

    const int bh = blockIdx.x & 31;           // (b*H + h) -> fixed XCD per head
    const int q0 = (blockIdx.x >> 5) << 7;    // 128-query tile start
    const int b  = bh >> 4;
    const int h  = bh & (Hh - 1);

    const int nvalid = valid[b];
    const int ntiles = (nvalid + KVB - 1) >> 7;

    const short* qb  = (const short*)(q  + (size_t)bh * Ll * Dd);
    const short* kb  = (const short*)(k  + (size_t)bh * Ll * Dd);
    const short* vtb = (const short*)(vt + (size_t)bh * Dd * Ll);

    // Q fragment: wave's 16 rows (linear layout)
    const int qrow = q0 + wave * 16 + l15;
    bf16x8 qa0 = *(const bf16x8*)(qb + (size_t)qrow * Dd + quad * 8);
    bf16x8 qa1 = *(const bf16x8*)(qb + (size_t)qrow * Dd + 32 + quad * 8);

    // swizzled group offsets (shorts) within a 64-short row, row&7 == l15&7
    const int g0 = ((quad ^ (l15 & 7)) << 3);
    const int g1 = (((quad + 4) ^ (l15 & 7)) << 3);

    // staging: K rows are keys (64 shorts each); thread covers 16B at tid*8 and +4096.
    // V transposed [d][key]: thread (d=tid>>3, grp=tid&7); chunk c at LDS offset c*4096.
    const short* vgp = vtb + (size_t)(tid >> 3) * Ll + ((tid & 7) << 3);
    short* ksl = &Ks[0][0] + tid * 8;
    short* vsl = &Vs[0][0] + tid * 8;
    const int lbuf = KVB * 64;          // 8192 shorts per buffer

    floatx4 O[4];
    float l_r = 0.f;
    #pragma unroll
    for (int nt = 0; nt < 4; nt++)
        #pragma unroll
        for (int r = 0; r < 4; r++) O[nt][r] = 0.f;

    // prologue: stage tile 0 (4 GLDs)
    GLD16(kb + tid * 8,        ksl);
    GLD16(kb + 4096 + tid * 8, ksl + 4096);
    GLD16(vgp,                 vsl);
    GLD16(vgp + 64,            vsl + 4096);

    short* Pw = &Ps[wave][0];

    for (int t = 0; t < ntiles; t++) {
        const int cur = t & 1;
        __builtin_amdgcn_s_barrier();   // all waves done reading buf cur^1
        if (t + 1 < ntiles) {
            const size_t s1 = (size_t)(t + 1) * KVB;
            GLD16(kb + s1 * 64 + tid * 8,        ksl + (cur ^ 1) * lbuf);
            GLD16(kb + s1 * 64 + 4096 + tid * 8, ksl + (cur ^ 1) * lbuf + 4096);
            GLD16(vgp + s1,                      vsl + (cur ^ 1) * lbuf);
            GLD16(vgp + s1 + 64,                 vsl + (cur ^ 1) * lbuf + 4096);
            VMCNT(4);   // tile t's 4 landed; tile t+1's 4 stay in flight
        } else {
            VMCNT(0);
        }

        const short* Kc = &Ks[cur][0];
        const short* Vc = &Vs[cur][0];

        #pragma unroll
        for (int c = 0; c < 2; c++) {
            // ---- S^T = K Q^T for 64-key chunk c: lane holds S[q=l15][key c*64+nt*16+quad*4+r]
            floatx4 S[4];
            #pragma unroll
            for (int nt = 0; nt < 4; nt++) {
                const short* krow = Kc + (c * 64 + nt * 16 + l15) * 64;
                bf16x8 ka0 = *(const bf16x8*)(krow + g0);
                bf16x8 ka1 = *(const bf16x8*)(krow + g1);
                floatx4 acc; acc[0] = acc[1] = acc[2] = acc[3] = 0.f;
                acc = __builtin_amdgcn_mfma_f32_16x16x32_bf16(ka0, qa0, acc, 0, 0, 0);
                acc = __builtin_amdgcn_mfma_f32_16x16x32_bf16(ka1, qa1, acc, 0, 0, 0);
                S[nt] = acc;
            }

            // ---- softmax: p = 2^S (log2e pre-folded into Q); mask keys >= nvalid ----
            const int kglob0 = t * KVB + c * 64;
            if (kglob0 + 64 <= nvalid) {
                #pragma unroll
                for (int nt = 0; nt < 4; nt++) {
                    float p0 = exp2_fast(S[nt][0]);
                    float p1 = exp2_fast(S[nt][1]);
                    float p2 = exp2_fast(S[nt][2]);
                    float p3 = exp2_fast(S[nt][3]);
                    l_r += (p0 + p1) + (p2 + p3);
                    int2 pw;
                    pw.x = cvtpk_bf16(p0, p1);
                    pw.y = cvtpk_bf16(p2, p3);
                    int grp = (2 * nt + (quad >> 1)) ^ (l15 & 7);
                    *(int2*)&Pw[l15 * 64 + (grp << 3) + ((quad & 1) << 2)] = pw;
                }
            } else {
                const int kb0 = kglob0 + quad * 4;
                #pragma unroll
                for (int nt = 0; nt < 4; nt++) {
                    float p[4];
                    #pragma unroll
                    for (int r = 0; r < 4; r++) {
                        p[r] = (kb0 + nt * 16 + r < nvalid) ? exp2_fast(S[nt][r]) : 0.f;
                        l_r += p[r];
                    }
                    int2 pw;
                    pw.x = cvtpk_bf16(p[0], p[1]);
                    pw.y = cvtpk_bf16(p[2], p[3]);
                    int grp = (2 * nt + (quad >> 1)) ^ (l15 & 7);
                    *(int2*)&Pw[l15 * 64 + (grp << 3) + ((quad & 1) << 2)] = pw;
                }
            }

            // ---- O^T += V^T P^T for chunk c ----
            bf16x8 pb0 = *(const bf16x8*)&Pw[l15 * 64 + ((quad ^ (l15 & 7)) << 3)];
            bf16x8 pb1 = *(const bf16x8*)&Pw[l15 * 64 + (((4 + quad) ^ (l15 & 7)) << 3)];
            #pragma unroll
            for (int nt = 0; nt < 4; nt++) {
                const short* vrow = Vc + c * 4096 + (nt * 16 + l15) * 64;
                bf16x8 va0 = *(const bf16x8*)(vrow + g0);
                bf16x8 va1 = *(const bf16x8*)(vrow + g1);
                O[nt] = __builtin_amdgcn_mfma_f32_16x16x32_bf16(va0, pb0, O[nt], 0, 0, 0);
                O[nt] = __builtin_amdgcn_mfma_f32_16x16x32_bf16(va1, pb1, O[nt], 0, 0, 0);
            }
        }
    }

    // ---- row-sum (quads hold same q) ----
    float l = l_r;
    l += __shfl_xor(l, 16);
    l += __shfl_xor(l, 32);
    const float inv = 1.0f / l;

    // ---- write ctx: lane holds O[q=l15][d=nt*16+quad*4+r] -> b64 stores ----
    {
        int row = q0 + wave * 16 + l15;
        short* cp = (short*)ctx + ((size_t)(b * Ll + row)) * Cc + h * Dd;
        #pragma unroll
        for (int nt = 0; nt < 4; nt++) {
            int2 ov;
            ov.x = cvtpk_bf16(O[nt][0] * inv, O[nt][1] * inv);
            ov.y = cvtpk_bf16(O[nt][2] * inv, O[nt][3] * inv);
            *(int2*)&cp[nt * 16 + quad * 4] = ov;
        }
    }
}

extern "C" void kernel_launch(void* const* d_in, const int* in_sizes, int n_in,
                              void* d_out, int out_size, void* d_ws, size_t ws_size,
                              hipStream_t stream) {
    const float* x    = (const float*)d_in[0];
    const int*   mask = (const int*)d_in[1];
    const float* Wq   = (const float*)d_in[2];
    const float* Wk   = (const float*)d_in[3];
    const float* Wv   = (const float*)d_in[4];
    const float* Wo   = (const float*)d_in[5];
    const float* bo   = (const float*)d_in[6];
    float* out = (float*)d_out;

    const size_t per = (size_t)Bb * Hh * Ll * Dd;   // 4 Mi elements
    bf16* qbuf = (bf16*)d_ws;
    bf16* kbuf = qbuf + per;            // compacted + swizzled
    bf16* vbuf = kbuf + per;            // compacted + transposed [B,H,D,L'] + swizzled
    bf16* xb   = vbuf + per;            // also used as ctx after x is dead
    bf16* wqkv = xb + per;              // [3072, 1024]
    bf16* wob  = wqkv + (size_t)3 * Cc * Cc;
    int*  cidx   = (int*)(wob + (size_t)Cc * Cc);
    int*  cvalid = cidx + Bb * Ll;
    bf16* ctx  = xb;

    const int M = Bb * Ll;   // 4096

    convert_scan<<<NCONV + Bb, 256, 0, stream>>>(
        x, Wq, Wk, Wv, Wo, xb, wqkv, wob, mask, cidx, cvalid);

    // fused QKV projection + RoPE + Q-scale(+log2e) + K/V compaction/swizzle + V-transpose
    // 128x128 tile, ring-3 counted-vmcnt, 512 threads (8 waves), 768 blocks = 3 blocks/CU
    dim3 gQKV(3 * Cc / 128, M / 128);   // (24, 32) = 768 blocks
    gemm_qkv<<<gQKV, 512, 0, stream>>>(xb, wqkv, qbuf, kbuf, vbuf, mask, cidx);

    attn_mfma<<<Bb * Hh * (Ll / 128), 512, 0, stream>>>(qbuf, kbuf, vbuf, cvalid, ctx);

    // output projection: 64x64 tile, 1024 blocks ~4/CU
    dim3 gOut(Cc / 64, M / 64);         // (16, 64) = 1024 blocks
    gemm_out<<<gOut, 256, 0, stream>>>(ctx, wob, out, bo);
}